// Round 1
// baseline (189.564 us; speedup 1.0000x reference)
//
#include <hip/hip_runtime.h>

// Problem constants (fixed by the reference)
#define BB 8
#define TT 512
#define SS 1024
#define HH 2048
#define LL (TT + SS - 1)   // 1535
#define TOK_DEFAULT_SPEECH 5

// ---------------------------------------------------------------------------
// Kernel 1: per-batch scalars from input_ids.
//   n = number of nonzero tokens (valid length; padding ids are 0, valid >= 1)
//   p = position of DEFAULT_SPEECH (unique per row)
// One wave (64 lanes) per batch row.
// ---------------------------------------------------------------------------
__global__ __launch_bounds__(64) void scalars_kernel(
    const int* __restrict__ input_ids, int* __restrict__ ws)
{
    const int b = blockIdx.x;
    const int lane = threadIdx.x;            // 0..63
    const int* row = input_ids + b * TT;
    int cnt = 0;
    int p = 0;
    #pragma unroll
    for (int t = lane; t < TT; t += 64) {
        const int id = row[t];
        cnt += (id != 0);
        if (id == TOK_DEFAULT_SPEECH) p = t;
    }
    #pragma unroll
    for (int off = 32; off > 0; off >>= 1) {
        cnt += __shfl_down(cnt, off);
        const int po = __shfl_down(p, off);
        p = (po > p) ? po : p;
    }
    if (lane == 0) {
        ws[b * 2 + 0] = cnt;   // n
        ws[b * 2 + 1] = p;     // placeholder position
    }
}

// ---------------------------------------------------------------------------
// Kernel 2: one block per output row (b, l). Pick the source row and copy
// H=2048 floats with 2x float4 per thread (256 threads). Thread 0 writes the
// mask and label scalars for this row.
// d_out layout (all float32): [B*L*H emb][B*L mask][B*L label]
// ---------------------------------------------------------------------------
__global__ __launch_bounds__(256) void merge_kernel(
    const float* __restrict__ speech,      // [B,S,H]
    const int*   __restrict__ slens,       // [B]
    const float* __restrict__ embeds,      // [B,T,H]
    const int*   __restrict__ labels,      // [B,T]
    const float* __restrict__ pw,          // [4,H]
    const int*   __restrict__ ws,          // [B*2] = (n, p)
    float*       __restrict__ out)
{
    const int l = blockIdx.x;              // 0..L-1
    const int b = blockIdx.y;              // 0..B-1
    const int n = ws[b * 2 + 0];
    const int p = ws[b * 2 + 1];
    const int s = slens[b];
    const int out_len = n + s - 1;
    const int k = l - (LL - out_len);      // position in unpadded merged seq

    const bool valid = (k >= 0) && (k < out_len);
    const bool in_sp = valid && (k >= p) && (k < p + s);

    const float* src = nullptr;
    float lbl = -100.0f;                   // IGNORE
    if (valid) {
        if (in_sp) {
            src = speech + ((size_t)(b * SS + (k - p))) * HH;
        } else {
            const int ti = (k < p) ? k : (k - s + 1);   // in [0, n-1]
            int r = -1;
            if (ti == 0)          r = 0;   // START_TEXT
            else if (ti == n - 1) r = 1;   // END_TEXT
            else if (ti == p - 1) r = 2;   // START_SPEECH
            else if (ti == p + 1) r = 3;   // END_SPEECH
            src = (r >= 0) ? (pw + (size_t)r * HH)
                           : (embeds + ((size_t)(b * TT + ti)) * HH);
            lbl = (float)labels[b * TT + ti];
        }
    }

    float* out_emb  = out + ((size_t)(b * LL + l)) * HH;
    float* out_mask = out + (size_t)BB * LL * HH;
    float* out_lbl  = out_mask + (size_t)BB * LL;

    const int tid = threadIdx.x;
    if (tid == 0) {
        out_mask[b * LL + l] = valid ? 1.0f : 0.0f;
        out_lbl [b * LL + l] = lbl;
    }

    float4* d4 = (float4*)out_emb;
    if (valid) {
        const float4* s4 = (const float4*)src;
        d4[tid]       = s4[tid];
        d4[tid + 256] = s4[tid + 256];
    } else {
        const float4 z = make_float4(0.f, 0.f, 0.f, 0.f);
        d4[tid]       = z;
        d4[tid + 256] = z;
    }
}

extern "C" void kernel_launch(void* const* d_in, const int* in_sizes, int n_in,
                              void* d_out, int out_size, void* d_ws, size_t ws_size,
                              hipStream_t stream)
{
    const float* speech = (const float*)d_in[0];   // [B,S,H]
    const int*   slens  = (const int*)  d_in[1];   // [B]
    const float* embeds = (const float*)d_in[2];   // [B,T,H]
    const int*   ids    = (const int*)  d_in[3];   // [B,T]
    // d_in[4] = attention_mask (unused; n derived from nonzero ids)
    const int*   labels = (const int*)  d_in[5];   // [B,T]
    const float* pw     = (const float*)d_in[6];   // [4,H]
    float* out = (float*)d_out;
    int*   ws  = (int*)d_ws;

    scalars_kernel<<<dim3(BB), dim3(64), 0, stream>>>(ids, ws);
    merge_kernel<<<dim3(LL, BB), dim3(256), 0, stream>>>(
        speech, slens, embeds, labels, pw, ws, out);
}

// Round 3
// 182.512 us; speedup vs baseline: 1.0386x; 1.0386x over previous
//
#include <hip/hip_runtime.h>

// Problem constants (fixed by the reference)
#define BB 8
#define TT 512
#define SS 1024
#define HH 2048
#define LL (TT + SS - 1)   // 1535
#define ROWS 4             // output rows per block
#define TOK_DEFAULT_SPEECH 5

// Native clang vector type — required by __builtin_nontemporal_* (HIP's
// float4 is a class and is rejected).
typedef float v4f __attribute__((ext_vector_type(4)));

// ---------------------------------------------------------------------------
// Fused kernel: one block handles ROWS consecutive output rows (b, l0..l0+3).
// Block first derives (n, p) from the L2-resident input_ids row (512 ints,
// 2 coalesced loads/thread + shuffle/LDS reduce), then streams each row with
// 2x 16B per thread (256 threads = 2048 floats = H). Nontemporal loads for
// single-use speech/embeds rows and nontemporal stores for the output stream;
// prompt_weight rows (reused across blocks) use cached loads.
// d_out layout (all float32): [B*L*H emb][B*L mask][B*L label]
// ---------------------------------------------------------------------------
__global__ __launch_bounds__(256) void merge_kernel(
    const float* __restrict__ speech,      // [B,S,H]
    const int*   __restrict__ slens,       // [B]
    const float* __restrict__ embeds,      // [B,T,H]
    const int*   __restrict__ ids,         // [B,T]
    const int*   __restrict__ labels,      // [B,T]
    const float* __restrict__ pw,          // [4,H]
    float*       __restrict__ out)
{
    const int b   = blockIdx.y;
    const int l0  = blockIdx.x * ROWS;
    const int tid = threadIdx.x;
    const int lane = tid & 63;
    const int wave = tid >> 6;

    // ---- block-wide (n, p) from input_ids row ----
    const int* row = ids + b * TT;
    const int idA = row[tid];
    const int idB = row[tid + 256];
    int cnt = (idA != 0) + (idB != 0);
    int p = 0;
    if (idA == TOK_DEFAULT_SPEECH) p = tid;
    if (idB == TOK_DEFAULT_SPEECH) p = tid + 256;
    #pragma unroll
    for (int off = 32; off > 0; off >>= 1) {
        cnt += __shfl_down(cnt, off);
        const int po = __shfl_down(p, off);
        p = (po > p) ? po : p;
    }
    __shared__ int scnt[4], spos[4], sh_np[2];
    if (lane == 0) { scnt[wave] = cnt; spos[wave] = p; }
    __syncthreads();
    if (tid == 0) {
        const int nn = scnt[0] + scnt[1] + scnt[2] + scnt[3];
        int pp = spos[0];
        pp = spos[1] > pp ? spos[1] : pp;
        pp = spos[2] > pp ? spos[2] : pp;
        pp = spos[3] > pp ? spos[3] : pp;
        sh_np[0] = nn;
        sh_np[1] = pp;
    }
    __syncthreads();
    const int n  = sh_np[0];
    const int pp = sh_np[1];
    const int s  = slens[b];
    const int out_len = n + s - 1;

    float* const out_mask = out + (size_t)BB * LL * HH;
    float* const out_lbl  = out_mask + (size_t)BB * LL;

    #pragma unroll
    for (int r = 0; r < ROWS; ++r) {
        const int l = l0 + r;
        if (l >= LL) break;                 // only last block.x is ragged

        const int k = l - (LL - out_len);   // position in unpadded merged seq
        const bool valid = (k >= 0) && (k < out_len);
        const bool in_sp = valid && (k >= pp) && (k < pp + s);

        v4f v0 = (v4f)(0.f);
        v4f v1 = (v4f)(0.f);
        float lbl = -100.0f;                // IGNORE

        if (valid) {
            if (in_sp) {
                const v4f* s4 = (const v4f*)
                    (speech + ((size_t)(b * SS + (k - pp))) * HH);
                v0 = __builtin_nontemporal_load(s4 + tid);
                v1 = __builtin_nontemporal_load(s4 + tid + 256);
            } else {
                const int ti = (k < pp) ? k : (k - s + 1);   // in [0, n-1]
                int pr = -1;
                if (ti == 0)           pr = 0;   // START_TEXT
                else if (ti == n - 1)  pr = 1;   // END_TEXT
                else if (ti == pp - 1) pr = 2;   // START_SPEECH
                else if (ti == pp + 1) pr = 3;   // END_SPEECH
                if (pr >= 0) {
                    const v4f* s4 = (const v4f*)(pw + (size_t)pr * HH);
                    v0 = s4[tid];
                    v1 = s4[tid + 256];
                } else {
                    const v4f* s4 = (const v4f*)
                        (embeds + ((size_t)(b * TT + ti)) * HH);
                    v0 = __builtin_nontemporal_load(s4 + tid);
                    v1 = __builtin_nontemporal_load(s4 + tid + 256);
                }
                lbl = (float)labels[b * TT + ti];
            }
        }

        v4f* d4 = (v4f*)(out + ((size_t)(b * LL + l)) * HH);
        __builtin_nontemporal_store(v0, d4 + tid);
        __builtin_nontemporal_store(v1, d4 + tid + 256);

        if (tid == 0) {
            out_mask[b * LL + l] = valid ? 1.0f : 0.0f;
            out_lbl [b * LL + l] = lbl;
        }
    }
}

extern "C" void kernel_launch(void* const* d_in, const int* in_sizes, int n_in,
                              void* d_out, int out_size, void* d_ws, size_t ws_size,
                              hipStream_t stream)
{
    const float* speech = (const float*)d_in[0];   // [B,S,H]
    const int*   slens  = (const int*)  d_in[1];   // [B]
    const float* embeds = (const float*)d_in[2];   // [B,T,H]
    const int*   ids    = (const int*)  d_in[3];   // [B,T]
    // d_in[4] = attention_mask (unused; n derived from nonzero ids)
    const int*   labels = (const int*)  d_in[5];   // [B,T]
    const float* pw     = (const float*)d_in[6];   // [4,H]
    float* out = (float*)d_out;

    const int gx = (LL + ROWS - 1) / ROWS;         // 384
    merge_kernel<<<dim3(gx, BB), dim3(256), 0, stream>>>(
        speech, slens, embeds, ids, labels, pw, out);
}